// Round 8
// baseline (126.124 us; speedup 1.0000x reference)
//
#include <hip/hip_runtime.h>

// Fused UpFIRDn2d via banded MFMA chain: crop(1) -> +bias -> repeat-up x2 ->
// sep 12-tap FIR -> leaky_relu(0.2)*sqrt(2) -> sep 12-tap FIR -> down x2.
// x: (8,64,130,130) f32; out: (8,64,128,128) f32.
//
// Round 14: two-channel blocks. R13's pipe accounting: per-block time ~= SUM
// of per-pipe busy cycles (VALU 3.7k + LDS 2.3k + VMEM 2.6k + MFMA 0.5k ~=
// 7.8k measured) -> pipes run SERIALLY because barrier phases correlate all
// waves onto one pipe at a time. Fix: each block processes channels bc and
// bc+256 with interleaved phases and separate LDS buffers: every tile does
// two independent MFMA chains sharing one const fragment -> inherent ILP-2,
// DS/MFMA/VALU mixed in every window, const loads and P0 addressing shared,
// barriers per unit work halved. Same bias ((bc+256)&63==bc&63) and same
// edge variants for both channels. LDS 2x38400 = 76800 B (dynamic; >64KB
// static limit) -> 2 blocks/CU, 16 waves. Grid (4,2,256) = 2048 blocks.
// Compiler-ILP lessons: R10/R13 both showed the scheduler sinks batched
// loads (VGPR 32/36) and sched_barrier(0) does not stop it; channel pairing
// gets ILP-2 without fighting the scheduler.
// Per-channel stage algebra (unchanged since round 8):
//   S1: B1[r][qq]  = sum_c  X[r][c]   * Gt[c][qq]    M80  N80  Kwin32 (25 tiles)
//   S2: U [pp][qq] = sum_r  G2[pp][r] * B1[r][qq]    M144 N80  Kwin32 (45), leaky
//   S3: T [a][qq]  = sum_pp D[a][pp]  * U[pp][qq]    M64  N80  Kwin64 (20)
//   S4: Out[a][j]  = sum_qq T[a][qq]  * D2t[qq][j]   M64  N32  Kwin64 (8)
// Edge clipping folded into 2 variants of D (by) and 3 of D2t (bx).

#define GAIN_C 1.4142135623730951f
#define NEG_C ((0.2f - 1.0f) * GAIN_C)

typedef short v8s __attribute__((ext_vector_type(8)));
typedef float v4f __attribute__((ext_vector_type(4)));

__device__ __forceinline__ int f2bf(float f) {   // fp32 -> bf16 bits (RNE)
    unsigned u = __float_as_uint(f);
    return (int)((u + 0x7FFFu + ((u >> 16) & 1u)) >> 16) & 0xFFFF;
}
__device__ __forceinline__ int pack_bf2(float a, float b) {
#if __has_builtin(__builtin_amdgcn_cvt_pk_bf16_f32)
    typedef __bf16 bf2 __attribute__((ext_vector_type(2)));
    bf2 r = __builtin_amdgcn_cvt_pk_bf16_f32(a, b);
    int o; __builtin_memcpy(&o, &r, 4); return o;
#else
    return f2bf(a) | (f2bf(b) << 16);
#endif
}

// band(x, q): up-conv weight linking local input index x to local up index q.
// qlim/xlim: valid extents of the local windows (cols: 74/43, rows: 138/75).
__device__ float band(int x, int q, int qlim, int xlim, const float* fu) {
    if (q >= qlim || x >= xlim || x < 0) return 0.f;
    int p = q >> 1, d = x - p;
    if (q & 1) {
        if (d < 0 || d > 6) return 0.f;
        if (d == 0) return fu[0];
        if (d == 6) return fu[11];
        return fu[2 * d - 1] + fu[2 * d];
    } else {
        if (d < 0 || d > 5) return 0.f;
        return fu[2 * d] + fu[2 * d + 1];
    }
}
// dband(o, q, v): down-conv weight, out index o, up index q; variant v:
// 0 = first tile (zero q<5), 2 = last tile (zero q>=qlim-5). qlim = up extent.
__device__ float dband(int o, int q, int v, int qlim, const float* fd) {
    if (q >= qlim || q < 0) return 0.f;
    if (v == 0 && q < 5) return 0.f;
    if (v == 2 && q >= qlim - 5) return 0.f;
    int k = q - 2 * o;
    if (k < 0 || k > 11) return 0.f;
    return fd[k];
}

// ws layout (bf16):
//   GtB 5nt x512            @0       (cols up: qlim 74, xlim 43, k0=min(8nt,16))
//   G2A 9mt x512            @2560    (rows up: qlim 138, xlim 75, k0=min(8mt,48))
//   DA  2v x (4mt x 2kt)x512 @7168   (rows dn: qlim 138, k0=min(32mt,80))
//   D2B 3v x (2nt x 2kt)x512 @15360  (cols dn: qlim 74,  k0=nt?16:0)
// Total 21504 shorts.  (Keep in sync with consumer kernel!)
__global__ __launch_bounds__(256) void build_consts(
    const float* __restrict__ fu, const float* __restrict__ fd,
    short* __restrict__ ws)
{
    int idx = blockIdx.x * 256 + threadIdx.x;   // grid covers 21504 exactly
    int l = (idx >> 3) & 63, j = idx & 7;
    int l15 = l & 15, kq = (l >> 4) * 8 + j;
    float val;
    if (idx < 2560) {                         // GtB: B-op, frag = nt
        int nt = idx >> 9;
        int k0 = 8 * nt < 16 ? 8 * nt : 16;
        val = band(k0 + kq, 16 * nt + l15, 74, 43, fu);
    } else if (idx < 7168) {                  // G2A: A-op, frag = mt (0..8)
        int mt = (idx - 2560) >> 9;
        int k0 = 8 * mt < 48 ? 8 * mt : 48;
        val = band(k0 + kq, 16 * mt + l15, 138, 75, fu);
    } else if (idx < 15360) {                 // DA: A-op, frag = (v, mt*2+kt)
        int rel = idx - 7168;
        int v = (rel >> 12) ? 2 : 0;          // by=0 -> v0, by=1 -> v2
        int fi = (rel & 4095) >> 9;
        int mt = fi >> 1, kt = fi & 1;
        int k0 = 32 * mt < 80 ? 32 * mt : 80;
        val = dband(16 * mt + l15, k0 + 32 * kt + kq, v, 138, fd);
    } else {                                  // D2B: B-op, frag = (v, nt*2+kt)
        int rel = idx - 15360;
        int v = rel >> 11, fi = (rel & 2047) >> 9;
        int nt = fi >> 1, kt = fi & 1;
        int k0 = nt ? 16 : 0;
        val = dband(16 * nt + l15, k0 + 32 * kt + kq, v, 74, fd);
    }
    ws[idx] = (short)f2bf(val);
}

#define XPITCH 48    // Xl  [80 r][48 c]    24 words/row (period-4, 2-way: free)
#define BPITCH 88    // B1t [80 qq][88 r]   44 words/row (period-8)
#define UPITCH 152   // Ut  [80 qq][152 pp] 76 words/row (period-8)
#define TPITCH 88    // T   [64 a][88 qq]
#define CHSTRIDE 19200  // shorts per channel's LDS region

// ---- Per-phase chunks, two channels interleaved per tile. ----
template<int K>
__device__ __forceinline__ void s1_chunk(
    int base, const short* __restrict__ GtB,
    const short* __restrict__ Xl0, const short* __restrict__ Xl1,
    short* __restrict__ B1t0, short* __restrict__ B1t1,
    int lane, int l15, int q4)
{
#pragma unroll
    for (int i = 0; i < K; ++i) {
        const int t = base + i;
        const int mt = t / 5, nt = t - mt * 5;
        const int k0 = 8 * nt < 16 ? 8 * nt : 16;
        v8s bf = *(const v8s*)&GtB[nt * 512 + lane * 8];       // shared
        const int aoff = (16 * mt + l15) * XPITCH + k0 + q4 * 8;
        v8s aA = *(const v8s*)&Xl0[aoff];
        v8s aB = *(const v8s*)&Xl1[aoff];
        v4f z = {0.f, 0.f, 0.f, 0.f};
        v4f accA = __builtin_amdgcn_mfma_f32_16x16x32_bf16(aA, bf, z, 0, 0, 0);
        v4f accB = __builtin_amdgcn_mfma_f32_16x16x32_bf16(aB, bf, z, 0, 0, 0);
        // C: col = qq = 16nt+l15, rows r = 16mt + q4*4 + i
        const int dst = (16 * nt + l15) * BPITCH + 16 * mt + q4 * 4;
        *(int2*)&B1t0[dst] = make_int2(pack_bf2(accA[0], accA[1]),
                                       pack_bf2(accA[2], accA[3]));
        *(int2*)&B1t1[dst] = make_int2(pack_bf2(accB[0], accB[1]),
                                       pack_bf2(accB[2], accB[3]));
    }
}

template<int K>
__device__ __forceinline__ void s2_chunk(
    int base, const short* __restrict__ G2A,
    const short* __restrict__ B1t0, const short* __restrict__ B1t1,
    short* __restrict__ Ut0, short* __restrict__ Ut1,
    int lane, int l15, int q4)
{
#pragma unroll
    for (int i = 0; i < K; ++i) {
        const int t = base + i;
        const int mt = t / 5, nt = t - mt * 5;
        const int k0 = 8 * mt < 48 ? 8 * mt : 48;
        v8s af = *(const v8s*)&G2A[mt * 512 + lane * 8];       // shared
        const int boff = (16 * nt + l15) * BPITCH + k0 + q4 * 8;
        v8s bA = *(const v8s*)&B1t0[boff];
        v8s bB = *(const v8s*)&B1t1[boff];
        v4f z = {0.f, 0.f, 0.f, 0.f};
        v4f accA = __builtin_amdgcn_mfma_f32_16x16x32_bf16(af, bA, z, 0, 0, 0);
        v4f accB = __builtin_amdgcn_mfma_f32_16x16x32_bf16(af, bB, z, 0, 0, 0);
#pragma unroll
        for (int j = 0; j < 4; ++j) {
            accA[j] = GAIN_C * accA[j] + NEG_C * fminf(accA[j], 0.f);
            accB[j] = GAIN_C * accB[j] + NEG_C * fminf(accB[j], 0.f);
        }
        // C: col = qq = 16nt+l15, rows pp = 16mt + q4*4 + i
        const int dst = (16 * nt + l15) * UPITCH + 16 * mt + q4 * 4;
        *(int2*)&Ut0[dst] = make_int2(pack_bf2(accA[0], accA[1]),
                                      pack_bf2(accA[2], accA[3]));
        *(int2*)&Ut1[dst] = make_int2(pack_bf2(accB[0], accB[1]),
                                      pack_bf2(accB[2], accB[3]));
    }
}

template<int K>
__device__ __forceinline__ void s3_chunk(
    int base, const short* __restrict__ DA,
    const short* __restrict__ Ut0, const short* __restrict__ Ut1,
    short* __restrict__ T0, short* __restrict__ T1,
    int lane, int l15, int q4)
{
#pragma unroll
    for (int i = 0; i < K; ++i) {
        const int t = base + i;
        const int mt = t / 5, nt = t - mt * 5;
        const int k0 = 32 * mt < 80 ? 32 * mt : 80;
        v8s a0 = *(const v8s*)&DA[(mt * 2 + 0) * 512 + lane * 8];  // shared
        v8s a1 = *(const v8s*)&DA[(mt * 2 + 1) * 512 + lane * 8];  // shared
        const int boff = (16 * nt + l15) * UPITCH + k0 + q4 * 8;
        v8s b0A = *(const v8s*)&Ut0[boff];
        v8s b1A = *(const v8s*)&Ut0[boff + 32];
        v8s b0B = *(const v8s*)&Ut1[boff];
        v8s b1B = *(const v8s*)&Ut1[boff + 32];
        v4f accA = {0.f, 0.f, 0.f, 0.f};
        v4f accB = {0.f, 0.f, 0.f, 0.f};
        accA = __builtin_amdgcn_mfma_f32_16x16x32_bf16(a0, b0A, accA, 0, 0, 0);
        accB = __builtin_amdgcn_mfma_f32_16x16x32_bf16(a0, b0B, accB, 0, 0, 0);
        accA = __builtin_amdgcn_mfma_f32_16x16x32_bf16(a1, b1A, accA, 0, 0, 0);
        accB = __builtin_amdgcn_mfma_f32_16x16x32_bf16(a1, b1B, accB, 0, 0, 0);
        // C: col = qq = 16nt+l15, rows a = 16mt + q4*4 + j  (b16 scatter)
        const int toff = (16 * mt + q4 * 4) * TPITCH + 16 * nt + l15;
        int pA01 = pack_bf2(accA[0], accA[1]);
        int pA23 = pack_bf2(accA[2], accA[3]);
        int pB01 = pack_bf2(accB[0], accB[1]);
        int pB23 = pack_bf2(accB[2], accB[3]);
        short* tA = (short*)&T0[toff];
        short* tB = (short*)&T1[toff];
        tA[0 * TPITCH] = (short)pA01; tA[1 * TPITCH] = (short)(pA01 >> 16);
        tA[2 * TPITCH] = (short)pA23; tA[3 * TPITCH] = (short)(pA23 >> 16);
        tB[0 * TPITCH] = (short)pB01; tB[1 * TPITCH] = (short)(pB01 >> 16);
        tB[2 * TPITCH] = (short)pB23; tB[3 * TPITCH] = (short)(pB23 >> 16);
    }
}

// LDS per channel (shorts): B1t @0 (7040) | Ut @7040 (12160) | Xl aliases Ut
// head (dead after S1) | T aliases B1t (dead after S2). 19200 shorts/ch,
// 2 channels = 38400 shorts = 76800 B (dynamic LDS) -> 2 blocks/CU.
__global__ __launch_bounds__(512, 4) void upfirdn_mfma(
    const float* __restrict__ xin_all,
    const float* __restrict__ bias,
    const short* __restrict__ cws,
    float* __restrict__ out)
{
    extern __shared__ short SH[];
    short* B1t0 = SH;                      // [80][88]
    short* Ut0  = SH + 7040;               // [80][152]
    short* Xl0  = SH + 7040;               // [80][48], dead after S1
    short* T0   = SH;                      // [64][88], written in S3
    short* B1t1 = SH + CHSTRIDE;
    short* Ut1  = SH + CHSTRIDE + 7040;
    short* Xl1  = SH + CHSTRIDE + 7040;
    short* T1   = SH + CHSTRIDE;

    const int tid  = threadIdx.x;
    const int lane = tid & 63, w = tid >> 6;          // 8 waves
    const int l15  = lane & 15, q4 = lane >> 4;
    const int bx = blockIdx.x, by = blockIdx.y, bc = blockIdx.z;  // bc 0..255
    const int i0 = by * 64, j0 = bx * 32;

    const short* GtB = cws;
    const short* G2A = cws + 2560;
    const short* DA  = cws + 7168  + (by ? 4096 : 0);
    const short* D2B = cws + 15360 + ((bx == 0) ? 0 : (bx == 3) ? 2 : 1) * 2048;

    // ---- Phase 0: load X tiles for channels bc and bc+256 (+bias, crop +1,
    // pads zero). 480 active threads, one 8-col slice per thread per channel;
    // address/validity computation shared between channels. ----
    if (tid < 480) {
        const int r  = tid / 6, c6 = tid - 6 * r;
        const int gr = i0 - 5 + r;
        int* dst0 = (int*)Xl0 + r * 24 + 4 * c6;
        int* dst1 = (int*)Xl1 + r * 24 + 4 * c6;
        if (r < 75 && (unsigned)gr < 128u) {
            const float* rowp0 = xin_all + (size_t)bc * (130 * 130)
                               + (gr + 1) * 130 + 1 + (j0 - 5);
            const float* rowp1 = rowp0 + (size_t)256 * (130 * 130);
            const float bv = bias[bc & 63];   // == bias[(bc+256)&63]
            const bool colInt = (bx == 1) | (bx == 2);
            float fA[8], fB[8];
#pragma unroll
            for (int j = 0; j < 8; ++j) {
                const int c = 8 * c6 + j;              // local col 0..47
                bool v = c < 43;
                if (!colInt) v = v && ((unsigned)(j0 - 5 + c) < 128u);
                fA[j] = v ? rowp0[c] + bv : 0.f;
                fB[j] = v ? rowp1[c] + bv : 0.f;
            }
            *(int2*)dst0 = make_int2(pack_bf2(fA[0], fA[1]), pack_bf2(fA[2], fA[3]));
            *(int2*)(dst0 + 2) =
                make_int2(pack_bf2(fA[4], fA[5]), pack_bf2(fA[6], fA[7]));
            *(int2*)dst1 = make_int2(pack_bf2(fB[0], fB[1]), pack_bf2(fB[2], fB[3]));
            *(int2*)(dst1 + 2) =
                make_int2(pack_bf2(fB[4], fB[5]), pack_bf2(fB[6], fB[7]));
        } else {
            *(int2*)dst0 = make_int2(0, 0);
            *(int2*)(dst0 + 2) = make_int2(0, 0);
            *(int2*)dst1 = make_int2(0, 0);
            *(int2*)(dst1 + 2) = make_int2(0, 0);
        }
    }
    __syncthreads();

    // ---- S1: 25 tile-pairs. wave 0: t 0..3; wave w>0: t 3w+1 .. 3w+3. ----
    if (w == 0) s1_chunk<4>(0,         GtB, Xl0, Xl1, B1t0, B1t1, lane, l15, q4);
    else        s1_chunk<3>(3 * w + 1, GtB, Xl0, Xl1, B1t0, B1t1, lane, l15, q4);
    __syncthreads();

    // ---- S2: 45 tile-pairs. waves 0..4: 6 @6w; waves 5..7: 5 @5w+5. ----
    if (w < 5) s2_chunk<6>(6 * w,     G2A, B1t0, B1t1, Ut0, Ut1, lane, l15, q4);
    else       s2_chunk<5>(5 * w + 5, G2A, B1t0, B1t1, Ut0, Ut1, lane, l15, q4);
    __syncthreads();

    // ---- S3: 20 tile-pairs. waves 0..3: 3 @3w; waves 4..7: 2 @2w+4. ----
    if (w < 4) s3_chunk<3>(3 * w,     DA, Ut0, Ut1, T0, T1, lane, l15, q4);
    else       s3_chunk<2>(2 * w + 4, DA, Ut0, Ut1, T0, T1, lane, l15, q4);
    __syncthreads();

    // ---- S4: Out = T * D2t.  8 tile-pairs: wave w -> (mt = w>>1, nt = w&1). ----
    {
        const int mt = w >> 1, nt = w & 1;
        const int k0 = nt ? 16 : 0;
        const int aoff = (16 * mt + l15) * TPITCH + k0 + q4 * 8;
        v8s aA0 = *(const v8s*)&T0[aoff];
        v8s aA1 = *(const v8s*)&T0[aoff + 32];
        v8s aB0 = *(const v8s*)&T1[aoff];
        v8s aB1 = *(const v8s*)&T1[aoff + 32];
        v8s b0 = *(const v8s*)&D2B[(nt * 2 + 0) * 512 + lane * 8];  // shared
        v8s b1 = *(const v8s*)&D2B[(nt * 2 + 1) * 512 + lane * 8];  // shared
        v4f accA = {0.f, 0.f, 0.f, 0.f};
        v4f accB = {0.f, 0.f, 0.f, 0.f};
        accA = __builtin_amdgcn_mfma_f32_16x16x32_bf16(aA0, b0, accA, 0, 0, 0);
        accB = __builtin_amdgcn_mfma_f32_16x16x32_bf16(aB0, b0, accB, 0, 0, 0);
        accA = __builtin_amdgcn_mfma_f32_16x16x32_bf16(aA1, b1, accA, 0, 0, 0);
        accB = __builtin_amdgcn_mfma_f32_16x16x32_bf16(aB1, b1, accB, 0, 0, 0);
        const size_t obase = (size_t)(i0 + 16 * mt + q4 * 4) * 128
                           + (j0 + 16 * nt + l15);
        float* opA = out + (size_t)bc * 16384 + obase;
        float* opB = opA + (size_t)256 * 16384;
#pragma unroll
        for (int i = 0; i < 4; ++i) {
            opA[i * 128] = accA[i];
            opB[i * 128] = accB[i];
        }
    }
}

extern "C" void kernel_launch(void* const* d_in, const int* in_sizes, int n_in,
                              void* d_out, int out_size, void* d_ws, size_t ws_size,
                              hipStream_t stream) {
    const float* x  = (const float*)d_in[0];
    const float* bs = (const float*)d_in[1];
    const float* fu = (const float*)d_in[2];
    const float* fd = (const float*)d_in[3];
    float* outp = (float*)d_out;
    short* ws = (short*)d_ws;

    build_consts<<<84, 256, 0, stream>>>(fu, fd, ws);    // 21504 elems
    upfirdn_mfma<<<dim3(4, 2, 256), 512, 76800, stream>>>(x, bs, ws, outp);
}

// Round 9
// 112.420 us; speedup vs baseline: 1.1219x; 1.1219x over previous
//
#include <hip/hip_runtime.h>

// Fused UpFIRDn2d via banded MFMA chain: crop(1) -> +bias -> repeat-up x2 ->
// sep 12-tap FIR -> leaky_relu(0.2)*sqrt(2) -> sep 12-tap FIR -> down x2.
// x: (8,64,130,130) f32; out: (8,64,128,128) f32.
//
// Round 15: pin the ILP batch with DATA dependencies. Every prior round
// measured VGPR 28-36: the compiler sinks operand loads to just before each
// MFMA, serializing each tile as ds_read(120cy)->mfma->pack->write. Per-wave
// chain ~15 tiles x ~240cy ~= 4-6k cy matches measured block wall time ->
// THIS is the invariant ~50us. sched_barrier(0) (R13) is only a scheduler
// hint and failed; asm volatile("" : "+v"(frag)) after the load loop is a
// data dependency the compiler cannot sink loads past. Windows of 3 tile
// pairs (2 for S3's 4-frag tiles) keep peak frag regs ~24-32 -> VGPR <= ~64,
// 4 blocks/CU retained. Verification: VGPR must rise to 50-70.
// Also: P0 loads are now UNCONDITIONAL dwordx4 pairs (worst-case +-5-float
// overhang provably stays inside the tensor allocation; validity via
// cndmask after load) -> no per-element exec branches, b128 Xl write.
// Base: round-10 kernel (best measured, 47us) + round-11 S3 cvt_pk pack.
//   S1: B1[r][qq]  = sum_c  X[r][c]   * Gt[c][qq]    M80  N80  Kwin32 (25 tiles)
//   S2: U [pp][qq] = sum_r  G2[pp][r] * B1[r][qq]    M144 N80  Kwin32 (45), leaky
//   S3: T [a][qq]  = sum_pp D[a][pp]  * U[pp][qq]    M64  N80  Kwin64 (20)
//   S4: Out[a][j]  = sum_qq T[a][qq]  * D2t[qq][j]   M64  N32  Kwin64 (8)
// Edge clipping folded into 2 variants of D (by) and 3 of D2t (bx).

#define GAIN_C 1.4142135623730951f
#define NEG_C ((0.2f - 1.0f) * GAIN_C)

typedef short v8s __attribute__((ext_vector_type(8)));
typedef float v4f __attribute__((ext_vector_type(4)));
typedef float f4u __attribute__((ext_vector_type(4), aligned(4)));  // align-4 dwordx4

__device__ __forceinline__ void pinv(v8s& x) { asm volatile("" : "+v"(x)); }

__device__ __forceinline__ int f2bf(float f) {   // fp32 -> bf16 bits (RNE)
    unsigned u = __float_as_uint(f);
    return (int)((u + 0x7FFFu + ((u >> 16) & 1u)) >> 16) & 0xFFFF;
}
__device__ __forceinline__ int pack_bf2(float a, float b) {
#if __has_builtin(__builtin_amdgcn_cvt_pk_bf16_f32)
    typedef __bf16 bf2 __attribute__((ext_vector_type(2)));
    bf2 r = __builtin_amdgcn_cvt_pk_bf16_f32(a, b);
    int o; __builtin_memcpy(&o, &r, 4); return o;
#else
    return f2bf(a) | (f2bf(b) << 16);
#endif
}

// band(x, q): up-conv weight linking local input index x to local up index q.
// qlim/xlim: valid extents of the local windows (cols: 74/43, rows: 138/75).
__device__ float band(int x, int q, int qlim, int xlim, const float* fu) {
    if (q >= qlim || x >= xlim || x < 0) return 0.f;
    int p = q >> 1, d = x - p;
    if (q & 1) {
        if (d < 0 || d > 6) return 0.f;
        if (d == 0) return fu[0];
        if (d == 6) return fu[11];
        return fu[2 * d - 1] + fu[2 * d];
    } else {
        if (d < 0 || d > 5) return 0.f;
        return fu[2 * d] + fu[2 * d + 1];
    }
}
// dband(o, q, v): down-conv weight, out index o, up index q; variant v:
// 0 = first tile (zero q<5), 2 = last tile (zero q>=qlim-5). qlim = up extent.
__device__ float dband(int o, int q, int v, int qlim, const float* fd) {
    if (q >= qlim || q < 0) return 0.f;
    if (v == 0 && q < 5) return 0.f;
    if (v == 2 && q >= qlim - 5) return 0.f;
    int k = q - 2 * o;
    if (k < 0 || k > 11) return 0.f;
    return fd[k];
}

// ws layout (bf16):
//   GtB 5nt x512            @0       (cols up: qlim 74, xlim 43, k0=min(8nt,16))
//   G2A 9mt x512            @2560    (rows up: qlim 138, xlim 75, k0=min(8mt,48))
//   DA  2v x (4mt x 2kt)x512 @7168   (rows dn: qlim 138, k0=min(32mt,80))
//   D2B 3v x (2nt x 2kt)x512 @15360  (cols dn: qlim 74,  k0=nt?16:0)
// Total 21504 shorts.  (Keep in sync with consumer kernel!)
__global__ __launch_bounds__(256) void build_consts(
    const float* __restrict__ fu, const float* __restrict__ fd,
    short* __restrict__ ws)
{
    int idx = blockIdx.x * 256 + threadIdx.x;   // grid covers 21504 exactly
    int l = (idx >> 3) & 63, j = idx & 7;
    int l15 = l & 15, kq = (l >> 4) * 8 + j;
    float val;
    if (idx < 2560) {                         // GtB: B-op, frag = nt
        int nt = idx >> 9;
        int k0 = 8 * nt < 16 ? 8 * nt : 16;
        val = band(k0 + kq, 16 * nt + l15, 74, 43, fu);
    } else if (idx < 7168) {                  // G2A: A-op, frag = mt (0..8)
        int mt = (idx - 2560) >> 9;
        int k0 = 8 * mt < 48 ? 8 * mt : 48;
        val = band(k0 + kq, 16 * mt + l15, 138, 75, fu);
    } else if (idx < 15360) {                 // DA: A-op, frag = (v, mt*2+kt)
        int rel = idx - 7168;
        int v = (rel >> 12) ? 2 : 0;          // by=0 -> v0, by=1 -> v2
        int fi = (rel & 4095) >> 9;
        int mt = fi >> 1, kt = fi & 1;
        int k0 = 32 * mt < 80 ? 32 * mt : 80;
        val = dband(16 * mt + l15, k0 + 32 * kt + kq, v, 138, fd);
    } else {                                  // D2B: B-op, frag = (v, nt*2+kt)
        int rel = idx - 15360;
        int v = rel >> 11, fi = (rel & 2047) >> 9;
        int nt = fi >> 1, kt = fi & 1;
        int k0 = nt ? 16 : 0;
        val = dband(16 * nt + l15, k0 + 32 * kt + kq, v, 74, fd);
    }
    ws[idx] = (short)f2bf(val);
}

#define XPITCH 48    // Xl  [80 r][48 c]    24 words/row (period-4, 2-way: free)
#define BPITCH 88    // B1t [80 qq][88 r]   44 words/row (period-8)
#define UPITCH 152   // Ut  [80 qq][152 pp] 76 words/row (period-8)
#define TPITCH 88    // T   [64 a][88 qq]

// ---- Pinned load windows: load N tile-operand sets, force them live via
// ---- asm data-dep (loads cannot sink), then run the N MFMAs + writes. ----
template<int N>
__device__ __forceinline__ void s1_window(
    int base, const short* __restrict__ GtB, const short* __restrict__ Xl,
    short* __restrict__ B1t, int lane, int l15, int q4)
{
    v8s a[N], bf[N];
    int dst[N];
#pragma unroll
    for (int i = 0; i < N; ++i) {
        const int t = base + i;
        const int mt = t / 5, nt = t - mt * 5;
        const int k0 = 8 * nt < 16 ? 8 * nt : 16;
        bf[i] = *(const v8s*)&GtB[nt * 512 + lane * 8];
        a[i]  = *(const v8s*)&Xl[(16 * mt + l15) * XPITCH + k0 + q4 * 8];
        dst[i] = (16 * nt + l15) * BPITCH + 16 * mt + q4 * 4;
    }
#pragma unroll
    for (int i = 0; i < N; ++i) { pinv(a[i]); pinv(bf[i]); }
#pragma unroll
    for (int i = 0; i < N; ++i) {
        v4f acc = {0.f, 0.f, 0.f, 0.f};
        acc = __builtin_amdgcn_mfma_f32_16x16x32_bf16(a[i], bf[i], acc, 0, 0, 0);
        // C: col = qq = 16nt+l15, rows r = 16mt + q4*4 + i
        *(int2*)&B1t[dst[i]] = make_int2(pack_bf2(acc[0], acc[1]),
                                         pack_bf2(acc[2], acc[3]));
    }
}

template<int N>
__device__ __forceinline__ void s2_window(
    int base, const short* __restrict__ G2A, const short* __restrict__ B1t,
    short* __restrict__ Ut, int lane, int l15, int q4)
{
    v8s af[N], b[N];
    int dst[N];
#pragma unroll
    for (int i = 0; i < N; ++i) {
        const int t = base + i;
        const int mt = t / 5, nt = t - mt * 5;
        const int k0 = 8 * mt < 48 ? 8 * mt : 48;
        af[i] = *(const v8s*)&G2A[mt * 512 + lane * 8];
        b[i]  = *(const v8s*)&B1t[(16 * nt + l15) * BPITCH + k0 + q4 * 8];
        dst[i] = (16 * nt + l15) * UPITCH + 16 * mt + q4 * 4;
    }
#pragma unroll
    for (int i = 0; i < N; ++i) { pinv(af[i]); pinv(b[i]); }
#pragma unroll
    for (int i = 0; i < N; ++i) {
        v4f acc = {0.f, 0.f, 0.f, 0.f};
        acc = __builtin_amdgcn_mfma_f32_16x16x32_bf16(af[i], b[i], acc, 0, 0, 0);
#pragma unroll
        for (int j = 0; j < 4; ++j)
            acc[j] = GAIN_C * acc[j] + NEG_C * fminf(acc[j], 0.f);
        // C: col = qq = 16nt+l15, rows pp = 16mt + q4*4 + i
        *(int2*)&Ut[dst[i]] = make_int2(pack_bf2(acc[0], acc[1]),
                                        pack_bf2(acc[2], acc[3]));
    }
}

template<int N>
__device__ __forceinline__ void s3_window(
    int base, const short* __restrict__ DA, const short* __restrict__ Ut,
    short* __restrict__ T, int lane, int l15, int q4)
{
    v8s a0[N], a1[N], b0[N], b1[N];
    int mtA[N], ntA[N];
#pragma unroll
    for (int i = 0; i < N; ++i) {
        const int t = base + i;
        const int mt = t / 5, nt = t - mt * 5;
        const int k0 = 32 * mt < 80 ? 32 * mt : 80;
        mtA[i] = mt; ntA[i] = nt;
        a0[i] = *(const v8s*)&DA[(mt * 2 + 0) * 512 + lane * 8];
        a1[i] = *(const v8s*)&DA[(mt * 2 + 1) * 512 + lane * 8];
        b0[i] = *(const v8s*)&Ut[(16 * nt + l15) * UPITCH + k0 + q4 * 8];
        b1[i] = *(const v8s*)&Ut[(16 * nt + l15) * UPITCH + k0 + 32 + q4 * 8];
    }
#pragma unroll
    for (int i = 0; i < N; ++i) {
        pinv(a0[i]); pinv(a1[i]); pinv(b0[i]); pinv(b1[i]);
    }
#pragma unroll
    for (int i = 0; i < N; ++i) {
        v4f acc = {0.f, 0.f, 0.f, 0.f};
        acc = __builtin_amdgcn_mfma_f32_16x16x32_bf16(a0[i], b0[i], acc, 0, 0, 0);
        acc = __builtin_amdgcn_mfma_f32_16x16x32_bf16(a1[i], b1[i], acc, 0, 0, 0);
        // C: col = qq = 16nt+l15, rows a = 16mt + q4*4 + j  (b16 scatter,
        // cvt_pk pair + hi-shift)
        int p01 = pack_bf2(acc[0], acc[1]);
        int p23 = pack_bf2(acc[2], acc[3]);
        short* tb = &T[(16 * mtA[i] + q4 * 4) * TPITCH + 16 * ntA[i] + l15];
        tb[0 * TPITCH] = (short)p01;
        tb[1 * TPITCH] = (short)(p01 >> 16);
        tb[2 * TPITCH] = (short)p23;
        tb[3 * TPITCH] = (short)(p23 >> 16);
    }
}

// LDS (shorts): B1t @0 (7040) | Ut @7040 (12160) | Xl aliases Ut head
// (dead after S1, Ut written in S2) | T aliases B1t (dead after S2).
// Total 19200 shorts = 38400 B -> 4 blocks/CU if VGPR <= 64.
__global__ __launch_bounds__(512, 6) void upfirdn_mfma(
    const float* __restrict__ xin_all,
    const float* __restrict__ bias,
    const short* __restrict__ cws,
    float* __restrict__ out)
{
    __shared__ __align__(16) short SH[19200];
    short* B1t = SH;            // [80][88]
    short* Ut  = SH + 7040;     // [80][152]
    short* Xl  = SH + 7040;     // [80][48], dead after S1
    short* T   = SH;            // [64][88], written in S3

    const int tid  = threadIdx.x;
    const int lane = tid & 63, w = tid >> 6;          // 8 waves
    const int l15  = lane & 15, q4 = lane >> 4;
    const int bx = blockIdx.x, by = blockIdx.y, bc = blockIdx.z;
    const int i0 = by * 64, j0 = bx * 32;

    const short* GtB = cws;
    const short* G2A = cws + 2560;
    const short* DA  = cws + 7168  + (by ? 4096 : 0);
    const short* D2B = cws + 15360 + ((bx == 0) ? 0 : (bx == 3) ? 2 : 1) * 2048;

    // ---- Phase 0: load X tile (crop +1, +bias), pads zero. 80 rows x 48
    // cols; 6 threads/row x 8 cols, 480 active. Loads are UNCONDITIONAL
    // dwordx4 pairs: absolute index = (gr+1)*130 + (j0-4) + 8*c6 + j with
    // gr+1 in [1,128], overhang <= 5 floats -> always inside the channel's
    // 130x130 allocation (min index 126, max 16774 < 16900). Validity
    // (c < 43, col in [0,128) for edge bx) applied by cndmask after load. ----
    if (tid < 480) {
        const int r  = tid / 6, c6 = tid - 6 * r;
        const int gr = i0 - 5 + r;
        int* dst = (int*)Xl + r * 24 + 4 * c6;
        if (r < 75 && (unsigned)gr < 128u) {
            const float* rowp = xin_all + (size_t)bc * (130 * 130)
                              + (gr + 1) * 130 + (j0 - 4) + 8 * c6;
            f4u v0 = *(const f4u*)rowp;
            f4u v1 = *(const f4u*)(rowp + 4);
            const float bv = bias[bc & 63];
            const bool colInt = (bx == 1) | (bx == 2);
            float f[8];
#pragma unroll
            for (int j = 0; j < 8; ++j) {
                const int c = 8 * c6 + j;              // local col 0..47
                bool valid = c < 43;
                if (!colInt) valid = valid && ((unsigned)(j0 - 5 + c) < 128u);
                const float xv = (j < 4) ? v0[j] : v1[j - 4];
                f[j] = valid ? xv + bv : 0.f;
            }
            *(int4*)dst = make_int4(pack_bf2(f[0], f[1]), pack_bf2(f[2], f[3]),
                                    pack_bf2(f[4], f[5]), pack_bf2(f[6], f[7]));
        } else {
            *(int4*)dst = make_int4(0, 0, 0, 0);
        }
    }
    __syncthreads();

    // ---- S1: 25 tiles. wave 0: t 0..3 (2+2); wave w>0: 3w+1..3w+3 (2+1). ----
    if (w == 0) {
        s1_window<2>(0, GtB, Xl, B1t, lane, l15, q4);
        s1_window<2>(2, GtB, Xl, B1t, lane, l15, q4);
    } else {
        s1_window<2>(3 * w + 1, GtB, Xl, B1t, lane, l15, q4);
        s1_window<1>(3 * w + 3, GtB, Xl, B1t, lane, l15, q4);
    }
    __syncthreads();

    // ---- S2: 45 tiles. waves 0..4: 6 @6w (3+3); waves 5..7: 5 @5w+5 (3+2). ----
    if (w < 5) {
        s2_window<3>(6 * w,     G2A, B1t, Ut, lane, l15, q4);
        s2_window<3>(6 * w + 3, G2A, B1t, Ut, lane, l15, q4);
    } else {
        s2_window<3>(5 * w + 5, G2A, B1t, Ut, lane, l15, q4);
        s2_window<2>(5 * w + 8, G2A, B1t, Ut, lane, l15, q4);
    }
    __syncthreads();

    // ---- S3: 20 tiles. waves 0..3: 3 @3w (2+1); waves 4..7: 2 @2w+4. ----
    if (w < 4) {
        s3_window<2>(3 * w,     DA, Ut, T, lane, l15, q4);
        s3_window<1>(3 * w + 2, DA, Ut, T, lane, l15, q4);
    } else {
        s3_window<2>(2 * w + 4, DA, Ut, T, lane, l15, q4);
    }
    __syncthreads();

    // ---- S4: Out = T * D2t.  8 tiles: wave w -> (mt = w>>1, nt = w&1). ----
    {
        const int mt = w >> 1, nt = w & 1;
        const int k0 = nt ? 16 : 0;
        v8s a0 = *(const v8s*)&T[(16 * mt + l15) * TPITCH + k0 + q4 * 8];
        v8s a1 = *(const v8s*)&T[(16 * mt + l15) * TPITCH + k0 + 32 + q4 * 8];
        v8s b0 = *(const v8s*)&D2B[(nt * 2 + 0) * 512 + lane * 8];
        v8s b1 = *(const v8s*)&D2B[(nt * 2 + 1) * 512 + lane * 8];
        pinv(a0); pinv(a1); pinv(b0); pinv(b1);
        v4f acc = {0.f, 0.f, 0.f, 0.f};
        acc = __builtin_amdgcn_mfma_f32_16x16x32_bf16(a0, b0, acc, 0, 0, 0);
        acc = __builtin_amdgcn_mfma_f32_16x16x32_bf16(a1, b1, acc, 0, 0, 0);
        float* op = out + (size_t)bc * 16384
                  + (size_t)(i0 + 16 * mt + q4 * 4) * 128 + (j0 + 16 * nt + l15);
#pragma unroll
        for (int i = 0; i < 4; ++i) op[i * 128] = acc[i];
    }
}

extern "C" void kernel_launch(void* const* d_in, const int* in_sizes, int n_in,
                              void* d_out, int out_size, void* d_ws, size_t ws_size,
                              hipStream_t stream) {
    const float* x  = (const float*)d_in[0];
    const float* bs = (const float*)d_in[1];
    const float* fu = (const float*)d_in[2];
    const float* fd = (const float*)d_in[3];
    float* outp = (float*)d_out;
    short* ws = (short*)d_ws;

    build_consts<<<84, 256, 0, stream>>>(fu, fd, ws);    // 21504 elems
    upfirdn_mfma<<<dim3(4, 2, 512), 512, 0, stream>>>(x, bs, ws, outp);
}

// Round 10
// 109.900 us; speedup vs baseline: 1.1476x; 1.0229x over previous
//
#include <hip/hip_runtime.h>

// Fused UpFIRDn2d via banded MFMA chain: crop(1) -> +bias -> repeat-up x2 ->
// sep 12-tap FIR -> leaky_relu(0.2)*sqrt(2) -> sep 12-tap FIR -> down x2.
// x: (8,64,130,130) f32; out: (8,64,128,128) f32.
//
// Round 16: compile-time tile schedules. R15 (pinned windows) gave the first
// real win (47.5 -> 42.6us) and left VALU the top pipe (62% = 26.4us), ~3x
// the necessary elementwise work. Main identified fat: chunk bases were
// RUNTIME (6*w etc.) so every tile paid a magic-mul div (t/5) and a full
// address build for each ds_read/ds_write/const load. This round makes the
// schedule compile-time: 8-way wave-uniform dispatch per phase into
// template<int W> bodies with literal window bases -> mt/nt/k0 constexpr ->
// one runtime LDS base per phase + offset:N immediates. Also folds GAIN_C
// into the DA table (S2 activation 3 -> 2 VALU/elem).
// Everything else = R15: pinned windows (asm "+v" data-dep stops load
// sinking), unconditional P0 dwordx4 loads, 64x32 tile, 8 waves, 38.4KB LDS.
//   S1: B1[r][qq]  = sum_c  X[r][c]   * Gt[c][qq]    M80  N80  Kwin32 (25 tiles)
//   S2: U [pp][qq] = sum_r  G2[pp][r] * B1[r][qq]    M144 N80  Kwin32 (45), leaky
//   S3: T [a][qq]  = sum_pp D[a][pp]  * U[pp][qq]    M64  N80  Kwin64 (20)
//   S4: Out[a][j]  = sum_qq T[a][qq]  * D2t[qq][j]   M64  N32  Kwin64 (8)
// Edge clipping folded into 2 variants of D (by) and 3 of D2t (bx).

#define GAIN_C 1.4142135623730951f
#define NEG2_C (0.2f - 1.0f)   // leaky residual; GAIN folded into DA table

typedef short v8s __attribute__((ext_vector_type(8)));
typedef float v4f __attribute__((ext_vector_type(4)));
typedef float f4u __attribute__((ext_vector_type(4), aligned(4)));  // align-4 dwordx4

__device__ __forceinline__ void pinv(v8s& x) { asm volatile("" : "+v"(x)); }

__device__ __forceinline__ int f2bf(float f) {   // fp32 -> bf16 bits (RNE)
    unsigned u = __float_as_uint(f);
    return (int)((u + 0x7FFFu + ((u >> 16) & 1u)) >> 16) & 0xFFFF;
}
__device__ __forceinline__ int pack_bf2(float a, float b) {
#if __has_builtin(__builtin_amdgcn_cvt_pk_bf16_f32)
    typedef __bf16 bf2 __attribute__((ext_vector_type(2)));
    bf2 r = __builtin_amdgcn_cvt_pk_bf16_f32(a, b);
    int o; __builtin_memcpy(&o, &r, 4); return o;
#else
    return f2bf(a) | (f2bf(b) << 16);
#endif
}

// band(x, q): up-conv weight linking local input index x to local up index q.
// qlim/xlim: valid extents of the local windows (cols: 74/43, rows: 138/75).
__device__ float band(int x, int q, int qlim, int xlim, const float* fu) {
    if (q >= qlim || x >= xlim || x < 0) return 0.f;
    int p = q >> 1, d = x - p;
    if (q & 1) {
        if (d < 0 || d > 6) return 0.f;
        if (d == 0) return fu[0];
        if (d == 6) return fu[11];
        return fu[2 * d - 1] + fu[2 * d];
    } else {
        if (d < 0 || d > 5) return 0.f;
        return fu[2 * d] + fu[2 * d + 1];
    }
}
// dband(o, q, v): down-conv weight, out index o, up index q; variant v:
// 0 = first tile (zero q<5), 2 = last tile (zero q>=qlim-5). qlim = up extent.
__device__ float dband(int o, int q, int v, int qlim, const float* fd) {
    if (q >= qlim || q < 0) return 0.f;
    if (v == 0 && q < 5) return 0.f;
    if (v == 2 && q >= qlim - 5) return 0.f;
    int k = q - 2 * o;
    if (k < 0 || k > 11) return 0.f;
    return fd[k];
}

// ws layout (bf16):
//   GtB 5nt x512            @0       (cols up: qlim 74, xlim 43, k0=min(8nt,16))
//   G2A 9mt x512            @2560    (rows up: qlim 138, xlim 75, k0=min(8mt,48))
//   DA  2v x (4mt x 2kt)x512 @7168   (rows dn: qlim 138, k0=min(32mt,80)),
//       PRE-SCALED by GAIN_C (leaky gain folded out of S2)
//   D2B 3v x (2nt x 2kt)x512 @15360  (cols dn: qlim 74,  k0=nt?16:0)
// Total 21504 shorts.  (Keep in sync with consumer kernel!)
__global__ __launch_bounds__(256) void build_consts(
    const float* __restrict__ fu, const float* __restrict__ fd,
    short* __restrict__ ws)
{
    int idx = blockIdx.x * 256 + threadIdx.x;   // grid covers 21504 exactly
    int l = (idx >> 3) & 63, j = idx & 7;
    int l15 = l & 15, kq = (l >> 4) * 8 + j;
    float val;
    if (idx < 2560) {                         // GtB: B-op, frag = nt
        int nt = idx >> 9;
        int k0 = 8 * nt < 16 ? 8 * nt : 16;
        val = band(k0 + kq, 16 * nt + l15, 74, 43, fu);
    } else if (idx < 7168) {                  // G2A: A-op, frag = mt (0..8)
        int mt = (idx - 2560) >> 9;
        int k0 = 8 * mt < 48 ? 8 * mt : 48;
        val = band(k0 + kq, 16 * mt + l15, 138, 75, fu);
    } else if (idx < 15360) {                 // DA: A-op, frag = (v, mt*2+kt)
        int rel = idx - 7168;
        int v = (rel >> 12) ? 2 : 0;          // by=0 -> v0, by=1 -> v2
        int fi = (rel & 4095) >> 9;
        int mt = fi >> 1, kt = fi & 1;
        int k0 = 32 * mt < 80 ? 32 * mt : 80;
        val = dband(16 * mt + l15, k0 + 32 * kt + kq, v, 138, fd) * GAIN_C;
    } else {                                  // D2B: B-op, frag = (v, nt*2+kt)
        int rel = idx - 15360;
        int v = rel >> 11, fi = (rel & 2047) >> 9;
        int nt = fi >> 1, kt = fi & 1;
        int k0 = nt ? 16 : 0;
        val = dband(16 * nt + l15, k0 + 32 * kt + kq, v, 74, fd);
    }
    ws[idx] = (short)f2bf(val);
}

#define XPITCH 48    // Xl  [80 r][48 c]    24 words/row (period-4, 2-way: free)
#define BPITCH 88    // B1t [80 qq][88 r]   44 words/row (period-8)
#define UPITCH 152   // Ut  [80 qq][152 pp] 76 words/row (period-8)
#define TPITCH 88    // T   [64 a][88 qq]

// ---- Pinned windows with COMPILE-TIME bases: mt/nt/k0 fold to literals,
// ---- addresses become one runtime base + offset:N immediates. ----
template<int BASE, int N>
__device__ __forceinline__ void s1_window(
    const short* __restrict__ GtB, const short* __restrict__ Xl,
    short* __restrict__ B1t, int lane, int l15, int q4)
{
    v8s a[N], bf[N];
#pragma unroll
    for (int i = 0; i < N; ++i) {
        const int t = BASE + i;                    // literal after unroll
        const int mt = t / 5, nt = t - mt * 5;
        const int k0 = 8 * nt < 16 ? 8 * nt : 16;
        bf[i] = *(const v8s*)&GtB[nt * 512 + lane * 8];
        a[i]  = *(const v8s*)&Xl[(16 * mt + l15) * XPITCH + k0 + q4 * 8];
    }
#pragma unroll
    for (int i = 0; i < N; ++i) { pinv(a[i]); pinv(bf[i]); }
#pragma unroll
    for (int i = 0; i < N; ++i) {
        const int t = BASE + i;
        const int mt = t / 5, nt = t - mt * 5;
        v4f acc = {0.f, 0.f, 0.f, 0.f};
        acc = __builtin_amdgcn_mfma_f32_16x16x32_bf16(a[i], bf[i], acc, 0, 0, 0);
        // C: col = qq = 16nt+l15, rows r = 16mt + q4*4 + i
        *(int2*)&B1t[(16 * nt + l15) * BPITCH + 16 * mt + q4 * 4] =
            make_int2(pack_bf2(acc[0], acc[1]), pack_bf2(acc[2], acc[3]));
    }
}

template<int BASE, int N>
__device__ __forceinline__ void s2_window(
    const short* __restrict__ G2A, const short* __restrict__ B1t,
    short* __restrict__ Ut, int lane, int l15, int q4)
{
    v8s af[N], b[N];
#pragma unroll
    for (int i = 0; i < N; ++i) {
        const int t = BASE + i;
        const int mt = t / 5, nt = t - mt * 5;
        const int k0 = 8 * mt < 48 ? 8 * mt : 48;
        af[i] = *(const v8s*)&G2A[mt * 512 + lane * 8];
        b[i]  = *(const v8s*)&B1t[(16 * nt + l15) * BPITCH + k0 + q4 * 8];
    }
#pragma unroll
    for (int i = 0; i < N; ++i) { pinv(af[i]); pinv(b[i]); }
#pragma unroll
    for (int i = 0; i < N; ++i) {
        const int t = BASE + i;
        const int mt = t / 5, nt = t - mt * 5;
        v4f acc = {0.f, 0.f, 0.f, 0.f};
        acc = __builtin_amdgcn_mfma_f32_16x16x32_bf16(af[i], b[i], acc, 0, 0, 0);
        // leaky residual only (GAIN folded into DA): x + (0.2-1)*min(x,0)
#pragma unroll
        for (int j = 0; j < 4; ++j)
            acc[j] = acc[j] + NEG2_C * fminf(acc[j], 0.f);
        // C: col = qq = 16nt+l15, rows pp = 16mt + q4*4 + i
        *(int2*)&Ut[(16 * nt + l15) * UPITCH + 16 * mt + q4 * 4] =
            make_int2(pack_bf2(acc[0], acc[1]), pack_bf2(acc[2], acc[3]));
    }
}

template<int BASE, int N>
__device__ __forceinline__ void s3_window(
    const short* __restrict__ DA, const short* __restrict__ Ut,
    short* __restrict__ T, int lane, int l15, int q4)
{
    v8s a0[N], a1[N], b0[N], b1[N];
#pragma unroll
    for (int i = 0; i < N; ++i) {
        const int t = BASE + i;
        const int mt = t / 5, nt = t - mt * 5;
        const int k0 = 32 * mt < 80 ? 32 * mt : 80;
        a0[i] = *(const v8s*)&DA[(mt * 2 + 0) * 512 + lane * 8];
        a1[i] = *(const v8s*)&DA[(mt * 2 + 1) * 512 + lane * 8];
        b0[i] = *(const v8s*)&Ut[(16 * nt + l15) * UPITCH + k0 + q4 * 8];
        b1[i] = *(const v8s*)&Ut[(16 * nt + l15) * UPITCH + k0 + 32 + q4 * 8];
    }
#pragma unroll
    for (int i = 0; i < N; ++i) {
        pinv(a0[i]); pinv(a1[i]); pinv(b0[i]); pinv(b1[i]);
    }
#pragma unroll
    for (int i = 0; i < N; ++i) {
        const int t = BASE + i;
        const int mt = t / 5, nt = t - mt * 5;
        v4f acc = {0.f, 0.f, 0.f, 0.f};
        acc = __builtin_amdgcn_mfma_f32_16x16x32_bf16(a0[i], b0[i], acc, 0, 0, 0);
        acc = __builtin_amdgcn_mfma_f32_16x16x32_bf16(a1[i], b1[i], acc, 0, 0, 0);
        // C: col = qq = 16nt+l15, rows a = 16mt + q4*4 + j  (b16 scatter)
        int p01 = pack_bf2(acc[0], acc[1]);
        int p23 = pack_bf2(acc[2], acc[3]);
        short* tb = &T[(16 * mt + q4 * 4) * TPITCH + 16 * nt + l15];
        tb[0 * TPITCH] = (short)p01;
        tb[1 * TPITCH] = (short)(p01 >> 16);
        tb[2 * TPITCH] = (short)p23;
        tb[3 * TPITCH] = (short)(p23 >> 16);
    }
}

// ---- Per-phase bodies with literal schedules (same coverage as R15). ----
template<int W>
__device__ __forceinline__ void s1_phase(
    const short* __restrict__ GtB, const short* __restrict__ Xl,
    short* __restrict__ B1t, int lane, int l15, int q4)
{
    if constexpr (W == 0) {
        s1_window<0, 2>(GtB, Xl, B1t, lane, l15, q4);
        s1_window<2, 2>(GtB, Xl, B1t, lane, l15, q4);
    } else {
        s1_window<3 * W + 1, 2>(GtB, Xl, B1t, lane, l15, q4);
        s1_window<3 * W + 3, 1>(GtB, Xl, B1t, lane, l15, q4);
    }
}

template<int W>
__device__ __forceinline__ void s2_phase(
    const short* __restrict__ G2A, const short* __restrict__ B1t,
    short* __restrict__ Ut, int lane, int l15, int q4)
{
    if constexpr (W < 5) {
        s2_window<6 * W,     3>(G2A, B1t, Ut, lane, l15, q4);
        s2_window<6 * W + 3, 3>(G2A, B1t, Ut, lane, l15, q4);
    } else {
        s2_window<5 * W + 5, 3>(G2A, B1t, Ut, lane, l15, q4);
        s2_window<5 * W + 8, 2>(G2A, B1t, Ut, lane, l15, q4);
    }
}

template<int W>
__device__ __forceinline__ void s3_phase(
    const short* __restrict__ DA, const short* __restrict__ Ut,
    short* __restrict__ T, int lane, int l15, int q4)
{
    if constexpr (W < 4) {
        s3_window<3 * W,     2>(DA, Ut, T, lane, l15, q4);
        s3_window<3 * W + 2, 1>(DA, Ut, T, lane, l15, q4);
    } else {
        s3_window<2 * W + 4, 2>(DA, Ut, T, lane, l15, q4);
    }
}

template<int W>
__device__ __forceinline__ void s4_phase(
    const short* __restrict__ T, const short* __restrict__ D2B,
    float* __restrict__ out, size_t obase_c, int i0, int j0, int l15, int q4,
    int lane)
{
    constexpr int mt = W >> 1, nt = W & 1;
    constexpr int k0 = nt ? 16 : 0;
    v8s a0 = *(const v8s*)&T[(16 * mt + l15) * TPITCH + k0 + q4 * 8];
    v8s a1 = *(const v8s*)&T[(16 * mt + l15) * TPITCH + k0 + 32 + q4 * 8];
    v8s b0 = *(const v8s*)&D2B[(nt * 2 + 0) * 512 + lane * 8];
    v8s b1 = *(const v8s*)&D2B[(nt * 2 + 1) * 512 + lane * 8];
    pinv(a0); pinv(a1); pinv(b0); pinv(b1);
    v4f acc = {0.f, 0.f, 0.f, 0.f};
    acc = __builtin_amdgcn_mfma_f32_16x16x32_bf16(a0, b0, acc, 0, 0, 0);
    acc = __builtin_amdgcn_mfma_f32_16x16x32_bf16(a1, b1, acc, 0, 0, 0);
    float* op = out + obase_c
              + (size_t)(i0 + 16 * mt + q4 * 4) * 128 + (j0 + 16 * nt + l15);
#pragma unroll
    for (int i = 0; i < 4; ++i) op[i * 128] = acc[i];
}

#define DISP8(CALL)                                                          \
    if      (w == 0) { CALL(0) } else if (w == 1) { CALL(1) }                \
    else if (w == 2) { CALL(2) } else if (w == 3) { CALL(3) }                \
    else if (w == 4) { CALL(4) } else if (w == 5) { CALL(5) }                \
    else if (w == 6) { CALL(6) } else { CALL(7) }

// LDS (shorts): B1t @0 (7040) | Ut @7040 (12160) | Xl aliases Ut head
// (dead after S1, Ut written in S2) | T aliases B1t (dead after S2).
// Total 19200 shorts = 38400 B -> 4 blocks/CU.
__global__ __launch_bounds__(512, 6) void upfirdn_mfma(
    const float* __restrict__ xin_all,
    const float* __restrict__ bias,
    const short* __restrict__ cws,
    float* __restrict__ out)
{
    __shared__ __align__(16) short SH[19200];
    short* B1t = SH;            // [80][88]
    short* Ut  = SH + 7040;     // [80][152]
    short* Xl  = SH + 7040;     // [80][48], dead after S1
    short* T   = SH;            // [64][88], written in S3

    const int tid  = threadIdx.x;
    const int lane = tid & 63, w = tid >> 6;          // 8 waves
    const int l15  = lane & 15, q4 = lane >> 4;
    const int bx = blockIdx.x, by = blockIdx.y, bc = blockIdx.z;
    const int i0 = by * 64, j0 = bx * 32;

    const short* GtB = cws;
    const short* G2A = cws + 2560;
    const short* DA  = cws + 7168  + (by ? 4096 : 0);
    const short* D2B = cws + 15360 + ((bx == 0) ? 0 : (bx == 3) ? 2 : 1) * 2048;

    // ---- Phase 0: load X tile (crop +1, +bias), pads zero. 80 rows x 48
    // cols; 6 threads/row x 8 cols, 480 active. Loads are UNCONDITIONAL
    // dwordx4 pairs: absolute index = (gr+1)*130 + (j0-4) + 8*c6 + j with
    // gr+1 in [1,128], overhang <= 5 floats -> always inside the channel's
    // 130x130 allocation. Validity applied by cndmask after load. ----
    if (tid < 480) {
        const int r  = tid / 6, c6 = tid - 6 * r;
        const int gr = i0 - 5 + r;
        int* dst = (int*)Xl + r * 24 + 4 * c6;
        if (r < 75 && (unsigned)gr < 128u) {
            const float* rowp = xin_all + (size_t)bc * (130 * 130)
                              + (gr + 1) * 130 + (j0 - 4) + 8 * c6;
            f4u v0 = *(const f4u*)rowp;
            f4u v1 = *(const f4u*)(rowp + 4);
            const float bv = bias[bc & 63];
            const bool colInt = (bx == 1) | (bx == 2);
            float f[8];
#pragma unroll
            for (int j = 0; j < 8; ++j) {
                const int c = 8 * c6 + j;              // local col 0..47
                bool valid = c < 43;
                if (!colInt) valid = valid && ((unsigned)(j0 - 5 + c) < 128u);
                const float xv = (j < 4) ? v0[j] : v1[j - 4];
                f[j] = valid ? xv + bv : 0.f;
            }
            *(int4*)dst = make_int4(pack_bf2(f[0], f[1]), pack_bf2(f[2], f[3]),
                                    pack_bf2(f[4], f[5]), pack_bf2(f[6], f[7]));
        } else {
            *(int4*)dst = make_int4(0, 0, 0, 0);
        }
    }
    __syncthreads();

    // ---- S1: 25 tiles, literal schedule per wave. ----
#define S1C(W) s1_phase<W>(GtB, Xl, B1t, lane, l15, q4);
    DISP8(S1C)
#undef S1C
    __syncthreads();

    // ---- S2: 45 tiles. ----
#define S2C(W) s2_phase<W>(G2A, B1t, Ut, lane, l15, q4);
    DISP8(S2C)
#undef S2C
    __syncthreads();

    // ---- S3: 20 tiles. ----
#define S3C(W) s3_phase<W>(DA, Ut, T, lane, l15, q4);
    DISP8(S3C)
#undef S3C
    __syncthreads();

    // ---- S4: 8 tiles, one per wave. ----
    const size_t obase_c = (size_t)bc * 16384;
#define S4C(W) s4_phase<W>(T, D2B, out, obase_c, i0, j0, l15, q4, lane);
    DISP8(S4C)
#undef S4C
}

extern "C" void kernel_launch(void* const* d_in, const int* in_sizes, int n_in,
                              void* d_out, int out_size, void* d_ws, size_t ws_size,
                              hipStream_t stream) {
    const float* x  = (const float*)d_in[0];
    const float* bs = (const float*)d_in[1];
    const float* fu = (const float*)d_in[2];
    const float* fd = (const float*)d_in[3];
    float* outp = (float*)d_out;
    short* ws = (short*)d_ws;

    build_consts<<<84, 256, 0, stream>>>(fu, fd, ws);    // 21504 elems
    upfirdn_mfma<<<dim3(4, 2, 512), 512, 0, stream>>>(x, bs, ws, outp);
}

// Round 11
// 108.048 us; speedup vs baseline: 1.1673x; 1.0171x over previous
//
#include <hip/hip_runtime.h>

// Fused UpFIRDn2d via banded MFMA chain: crop(1) -> +bias -> repeat-up x2 ->
// sep 12-tap FIR -> leaky_relu(0.2)*sqrt(2) -> sep 12-tap FIR -> down x2.
// x: (8,64,130,130) f32; out: (8,64,128,128) f32.
//
// Round 17: full-phase windows + const-frag dedup. R16 cut VALU 62->47% with
// zero time change -> VALU not critical; remaining cost is per-wave phase
// latency (2-3 sequential ~320cy windows per phase). This round: ONE pinned
// window per wave per phase (S1 3-4 tiles, S2 5-6, S3 2-3), VMEM const
// loads issued before LDS reads (latencies overlap), and A-fragment dedup
// within a window (S2: mt=t/5 spans <=2 values -> 2 af loads not 6; same for
// S3 a0/a1). Peak live set ~8-10 v8s -> VGPR ~56, 4 blocks/CU retained.
// Verification: VGPR must rise to 44-64. If dur >= 42us anyway, window-
// latency lever is exhausted -> pivot to DS-traffic restructure.
// Carried: R15 pinned windows (asm "+v"), R16 compile-time schedules +
// GAIN folded into DA, unconditional P0 dwordx4, 64x32 tile, 38.4KB LDS.
//   S1: B1[r][qq]  = sum_c  X[r][c]   * Gt[c][qq]    M80  N80  Kwin32 (25 tiles)
//   S2: U [pp][qq] = sum_r  G2[pp][r] * B1[r][qq]    M144 N80  Kwin32 (45), leaky
//   S3: T [a][qq]  = sum_pp D[a][pp]  * U[pp][qq]    M64  N80  Kwin64 (20)
//   S4: Out[a][j]  = sum_qq T[a][qq]  * D2t[qq][j]   M64  N32  Kwin64 (8)
// Edge clipping folded into 2 variants of D (by) and 3 of D2t (bx).

#define GAIN_C 1.4142135623730951f
#define NEG2_C (0.2f - 1.0f)   // leaky residual; GAIN folded into DA table

typedef short v8s __attribute__((ext_vector_type(8)));
typedef float v4f __attribute__((ext_vector_type(4)));
typedef float f4u __attribute__((ext_vector_type(4), aligned(4)));  // align-4 dwordx4

__device__ __forceinline__ void pinv(v8s& x) { asm volatile("" : "+v"(x)); }

__device__ __forceinline__ int f2bf(float f) {   // fp32 -> bf16 bits (RNE)
    unsigned u = __float_as_uint(f);
    return (int)((u + 0x7FFFu + ((u >> 16) & 1u)) >> 16) & 0xFFFF;
}
__device__ __forceinline__ int pack_bf2(float a, float b) {
#if __has_builtin(__builtin_amdgcn_cvt_pk_bf16_f32)
    typedef __bf16 bf2 __attribute__((ext_vector_type(2)));
    bf2 r = __builtin_amdgcn_cvt_pk_bf16_f32(a, b);
    int o; __builtin_memcpy(&o, &r, 4); return o;
#else
    return f2bf(a) | (f2bf(b) << 16);
#endif
}

// band(x, q): up-conv weight linking local input index x to local up index q.
// qlim/xlim: valid extents of the local windows (cols: 74/43, rows: 138/75).
__device__ float band(int x, int q, int qlim, int xlim, const float* fu) {
    if (q >= qlim || x >= xlim || x < 0) return 0.f;
    int p = q >> 1, d = x - p;
    if (q & 1) {
        if (d < 0 || d > 6) return 0.f;
        if (d == 0) return fu[0];
        if (d == 6) return fu[11];
        return fu[2 * d - 1] + fu[2 * d];
    } else {
        if (d < 0 || d > 5) return 0.f;
        return fu[2 * d] + fu[2 * d + 1];
    }
}
// dband(o, q, v): down-conv weight, out index o, up index q; variant v:
// 0 = first tile (zero q<5), 2 = last tile (zero q>=qlim-5). qlim = up extent.
__device__ float dband(int o, int q, int v, int qlim, const float* fd) {
    if (q >= qlim || q < 0) return 0.f;
    if (v == 0 && q < 5) return 0.f;
    if (v == 2 && q >= qlim - 5) return 0.f;
    int k = q - 2 * o;
    if (k < 0 || k > 11) return 0.f;
    return fd[k];
}

// ws layout (bf16):
//   GtB 5nt x512            @0       (cols up: qlim 74, xlim 43, k0=min(8nt,16))
//   G2A 9mt x512            @2560    (rows up: qlim 138, xlim 75, k0=min(8mt,48))
//   DA  2v x (4mt x 2kt)x512 @7168   (rows dn: qlim 138, k0=min(32mt,80)),
//       PRE-SCALED by GAIN_C (leaky gain folded out of S2)
//   D2B 3v x (2nt x 2kt)x512 @15360  (cols dn: qlim 74,  k0=nt?16:0)
// Total 21504 shorts.  (Keep in sync with consumer kernel!)
__global__ __launch_bounds__(256) void build_consts(
    const float* __restrict__ fu, const float* __restrict__ fd,
    short* __restrict__ ws)
{
    int idx = blockIdx.x * 256 + threadIdx.x;   // grid covers 21504 exactly
    int l = (idx >> 3) & 63, j = idx & 7;
    int l15 = l & 15, kq = (l >> 4) * 8 + j;
    float val;
    if (idx < 2560) {                         // GtB: B-op, frag = nt
        int nt = idx >> 9;
        int k0 = 8 * nt < 16 ? 8 * nt : 16;
        val = band(k0 + kq, 16 * nt + l15, 74, 43, fu);
    } else if (idx < 7168) {                  // G2A: A-op, frag = mt (0..8)
        int mt = (idx - 2560) >> 9;
        int k0 = 8 * mt < 48 ? 8 * mt : 48;
        val = band(k0 + kq, 16 * mt + l15, 138, 75, fu);
    } else if (idx < 15360) {                 // DA: A-op, frag = (v, mt*2+kt)
        int rel = idx - 7168;
        int v = (rel >> 12) ? 2 : 0;          // by=0 -> v0, by=1 -> v2
        int fi = (rel & 4095) >> 9;
        int mt = fi >> 1, kt = fi & 1;
        int k0 = 32 * mt < 80 ? 32 * mt : 80;
        val = dband(16 * mt + l15, k0 + 32 * kt + kq, v, 138, fd) * GAIN_C;
    } else {                                  // D2B: B-op, frag = (v, nt*2+kt)
        int rel = idx - 15360;
        int v = rel >> 11, fi = (rel & 2047) >> 9;
        int nt = fi >> 1, kt = fi & 1;
        int k0 = nt ? 16 : 0;
        val = dband(16 * nt + l15, k0 + 32 * kt + kq, v, 74, fd);
    }
    ws[idx] = (short)f2bf(val);
}

#define XPITCH 48    // Xl  [80 r][48 c]    24 words/row (period-4, 2-way: free)
#define BPITCH 88    // B1t [80 qq][88 r]   44 words/row (period-8)
#define UPITCH 152   // Ut  [80 qq][152 pp] 76 words/row (period-8)
#define TPITCH 88    // T   [64 a][88 qq]

// ---- Full-phase pinned windows. Load order: VMEM consts first (200cy),
// ---- then LDS reads (120cy) -> latencies overlap; pin; then MFMAs+writes. ----
template<int BASE, int N>
__device__ __forceinline__ void s1_window(
    const short* __restrict__ GtB, const short* __restrict__ Xl,
    short* __restrict__ B1t, int lane, int l15, int q4)
{
    v8s bf[N], a[N];
#pragma unroll
    for (int i = 0; i < N; ++i) {              // VMEM first
        const int t = BASE + i;
        const int nt = t - (t / 5) * 5;
        bf[i] = *(const v8s*)&GtB[nt * 512 + lane * 8];
    }
#pragma unroll
    for (int i = 0; i < N; ++i) {              // then LDS
        const int t = BASE + i;
        const int mt = t / 5, nt = t - mt * 5;
        const int k0 = 8 * nt < 16 ? 8 * nt : 16;
        a[i] = *(const v8s*)&Xl[(16 * mt + l15) * XPITCH + k0 + q4 * 8];
    }
#pragma unroll
    for (int i = 0; i < N; ++i) { pinv(bf[i]); pinv(a[i]); }
#pragma unroll
    for (int i = 0; i < N; ++i) {
        const int t = BASE + i;
        const int mt = t / 5, nt = t - mt * 5;
        v4f acc = {0.f, 0.f, 0.f, 0.f};
        acc = __builtin_amdgcn_mfma_f32_16x16x32_bf16(a[i], bf[i], acc, 0, 0, 0);
        // C: col = qq = 16nt+l15, rows r = 16mt + q4*4 + i
        *(int2*)&B1t[(16 * nt + l15) * BPITCH + 16 * mt + q4 * 4] =
            make_int2(pack_bf2(acc[0], acc[1]), pack_bf2(acc[2], acc[3]));
    }
}

template<int BASE, int N>
__device__ __forceinline__ void s2_window(
    const short* __restrict__ G2A, const short* __restrict__ B1t,
    short* __restrict__ Ut, int lane, int l15, int q4)
{
    constexpr int MT0 = BASE / 5;
    constexpr int MTL = (BASE + N - 1) / 5;     // <= MT0+1 for N<=6
    v8s af0, af1{};
    af0 = *(const v8s*)&G2A[MT0 * 512 + lane * 8];          // VMEM, dedup'd
    if constexpr (MTL != MT0)
        af1 = *(const v8s*)&G2A[MTL * 512 + lane * 8];
    v8s b[N];
#pragma unroll
    for (int i = 0; i < N; ++i) {              // LDS
        const int t = BASE + i;
        const int mt = t / 5, nt = t - mt * 5;
        const int k0 = 8 * mt < 48 ? 8 * mt : 48;
        b[i] = *(const v8s*)&B1t[(16 * nt + l15) * BPITCH + k0 + q4 * 8];
    }
    pinv(af0);
    if constexpr (MTL != MT0) pinv(af1);
#pragma unroll
    for (int i = 0; i < N; ++i) pinv(b[i]);
#pragma unroll
    for (int i = 0; i < N; ++i) {
        const int t = BASE + i;
        const int mt = t / 5, nt = t - mt * 5;
        const v8s af = (mt == MT0) ? af0 : af1;   // constexpr-folded select
        v4f acc = {0.f, 0.f, 0.f, 0.f};
        acc = __builtin_amdgcn_mfma_f32_16x16x32_bf16(af, b[i], acc, 0, 0, 0);
        // leaky residual only (GAIN folded into DA): x + (0.2-1)*min(x,0)
#pragma unroll
        for (int j = 0; j < 4; ++j)
            acc[j] = acc[j] + NEG2_C * fminf(acc[j], 0.f);
        // C: col = qq = 16nt+l15, rows pp = 16mt + q4*4 + i
        *(int2*)&Ut[(16 * nt + l15) * UPITCH + 16 * mt + q4 * 4] =
            make_int2(pack_bf2(acc[0], acc[1]), pack_bf2(acc[2], acc[3]));
    }
}

template<int BASE, int N>
__device__ __forceinline__ void s3_window(
    const short* __restrict__ DA, const short* __restrict__ Ut,
    short* __restrict__ T, int lane, int l15, int q4)
{
    constexpr int MT0 = BASE / 5;
    constexpr int MTL = (BASE + N - 1) / 5;
    v8s a00, a01, a10{}, a11{};
    a00 = *(const v8s*)&DA[(MT0 * 2 + 0) * 512 + lane * 8];  // VMEM, dedup'd
    a01 = *(const v8s*)&DA[(MT0 * 2 + 1) * 512 + lane * 8];
    if constexpr (MTL != MT0) {
        a10 = *(const v8s*)&DA[(MTL * 2 + 0) * 512 + lane * 8];
        a11 = *(const v8s*)&DA[(MTL * 2 + 1) * 512 + lane * 8];
    }
    v8s b0[N], b1[N];
#pragma unroll
    for (int i = 0; i < N; ++i) {              // LDS
        const int t = BASE + i;
        const int mt = t / 5, nt = t - mt * 5;
        const int k0 = 32 * mt < 80 ? 32 * mt : 80;
        b0[i] = *(const v8s*)&Ut[(16 * nt + l15) * UPITCH + k0 + q4 * 8];
        b1[i] = *(const v8s*)&Ut[(16 * nt + l15) * UPITCH + k0 + 32 + q4 * 8];
    }
    pinv(a00); pinv(a01);
    if constexpr (MTL != MT0) { pinv(a10); pinv(a11); }
#pragma unroll
    for (int i = 0; i < N; ++i) { pinv(b0[i]); pinv(b1[i]); }
#pragma unroll
    for (int i = 0; i < N; ++i) {
        const int t = BASE + i;
        const int mt = t / 5, nt = t - mt * 5;
        const v8s a0 = (mt == MT0) ? a00 : a10;   // constexpr-folded
        const v8s a1 = (mt == MT0) ? a01 : a11;
        v4f acc = {0.f, 0.f, 0.f, 0.f};
        acc = __builtin_amdgcn_mfma_f32_16x16x32_bf16(a0, b0[i], acc, 0, 0, 0);
        acc = __builtin_amdgcn_mfma_f32_16x16x32_bf16(a1, b1[i], acc, 0, 0, 0);
        // C: col = qq = 16nt+l15, rows a = 16mt + q4*4 + j  (b16 scatter)
        int p01 = pack_bf2(acc[0], acc[1]);
        int p23 = pack_bf2(acc[2], acc[3]);
        short* tb = &T[(16 * mt + q4 * 4) * TPITCH + 16 * nt + l15];
        tb[0 * TPITCH] = (short)p01;
        tb[1 * TPITCH] = (short)(p01 >> 16);
        tb[2 * TPITCH] = (short)p23;
        tb[3 * TPITCH] = (short)(p23 >> 16);
    }
}

// ---- Per-phase bodies: ONE window per wave per phase. ----
template<int W>
__device__ __forceinline__ void s1_phase(
    const short* __restrict__ GtB, const short* __restrict__ Xl,
    short* __restrict__ B1t, int lane, int l15, int q4)
{
    if constexpr (W == 0) s1_window<0, 4>(GtB, Xl, B1t, lane, l15, q4);
    else                  s1_window<3 * W + 1, 3>(GtB, Xl, B1t, lane, l15, q4);
}

template<int W>
__device__ __forceinline__ void s2_phase(
    const short* __restrict__ G2A, const short* __restrict__ B1t,
    short* __restrict__ Ut, int lane, int l15, int q4)
{
    if constexpr (W < 5) s2_window<6 * W, 6>(G2A, B1t, Ut, lane, l15, q4);
    else                 s2_window<5 * W + 5, 5>(G2A, B1t, Ut, lane, l15, q4);
}

template<int W>
__device__ __forceinline__ void s3_phase(
    const short* __restrict__ DA, const short* __restrict__ Ut,
    short* __restrict__ T, int lane, int l15, int q4)
{
    if constexpr (W < 4) s3_window<3 * W, 3>(DA, Ut, T, lane, l15, q4);
    else                 s3_window<2 * W + 4, 2>(DA, Ut, T, lane, l15, q4);
}

template<int W>
__device__ __forceinline__ void s4_phase(
    const short* __restrict__ T, const short* __restrict__ D2B,
    float* __restrict__ out, size_t obase_c, int i0, int j0, int l15, int q4,
    int lane)
{
    constexpr int mt = W >> 1, nt = W & 1;
    constexpr int k0 = nt ? 16 : 0;
    v8s b0 = *(const v8s*)&D2B[(nt * 2 + 0) * 512 + lane * 8];  // VMEM first
    v8s b1 = *(const v8s*)&D2B[(nt * 2 + 1) * 512 + lane * 8];
    v8s a0 = *(const v8s*)&T[(16 * mt + l15) * TPITCH + k0 + q4 * 8];
    v8s a1 = *(const v8s*)&T[(16 * mt + l15) * TPITCH + k0 + 32 + q4 * 8];
    pinv(b0); pinv(b1); pinv(a0); pinv(a1);
    v4f acc = {0.f, 0.f, 0.f, 0.f};
    acc = __builtin_amdgcn_mfma_f32_16x16x32_bf16(a0, b0, acc, 0, 0, 0);
    acc = __builtin_amdgcn_mfma_f32_16x16x32_bf16(a1, b1, acc, 0, 0, 0);
    float* op = out + obase_c
              + (size_t)(i0 + 16 * mt + q4 * 4) * 128 + (j0 + 16 * nt + l15);
#pragma unroll
    for (int i = 0; i < 4; ++i) op[i * 128] = acc[i];
}

#define DISP8(CALL)                                                          \
    if      (w == 0) { CALL(0) } else if (w == 1) { CALL(1) }                \
    else if (w == 2) { CALL(2) } else if (w == 3) { CALL(3) }                \
    else if (w == 4) { CALL(4) } else if (w == 5) { CALL(5) }                \
    else if (w == 6) { CALL(6) } else { CALL(7) }

// LDS (shorts): B1t @0 (7040) | Ut @7040 (12160) | Xl aliases Ut head
// (dead after S1, Ut written in S2) | T aliases B1t (dead after S2).
// Total 19200 shorts = 38400 B -> 4 blocks/CU.
__global__ __launch_bounds__(512, 6) void upfirdn_mfma(
    const float* __restrict__ xin_all,
    const float* __restrict__ bias,
    const short* __restrict__ cws,
    float* __restrict__ out)
{
    __shared__ __align__(16) short SH[19200];
    short* B1t = SH;            // [80][88]
    short* Ut  = SH + 7040;     // [80][152]
    short* Xl  = SH + 7040;     // [80][48], dead after S1
    short* T   = SH;            // [64][88], written in S3

    const int tid  = threadIdx.x;
    const int lane = tid & 63, w = tid >> 6;          // 8 waves
    const int l15  = lane & 15, q4 = lane >> 4;
    const int bx = blockIdx.x, by = blockIdx.y, bc = blockIdx.z;
    const int i0 = by * 64, j0 = bx * 32;

    const short* GtB = cws;
    const short* G2A = cws + 2560;
    const short* DA  = cws + 7168  + (by ? 4096 : 0);
    const short* D2B = cws + 15360 + ((bx == 0) ? 0 : (bx == 3) ? 2 : 1) * 2048;

    // ---- Phase 0: load X tile (crop +1, +bias), pads zero. 80 rows x 48
    // cols; 6 threads/row x 8 cols, 480 active. Loads are UNCONDITIONAL
    // dwordx4 pairs: absolute index = (gr+1)*130 + (j0-4) + 8*c6 + j with
    // gr+1 in [1,128], overhang <= 5 floats -> always inside the channel's
    // 130x130 allocation. Validity applied by cndmask after load. ----
    if (tid < 480) {
        const int r  = tid / 6, c6 = tid - 6 * r;
        const int gr = i0 - 5 + r;
        int* dst = (int*)Xl + r * 24 + 4 * c6;
        if (r < 75 && (unsigned)gr < 128u) {
            const float* rowp = xin_all + (size_t)bc * (130 * 130)
                              + (gr + 1) * 130 + (j0 - 4) + 8 * c6;
            f4u v0 = *(const f4u*)rowp;
            f4u v1 = *(const f4u*)(rowp + 4);
            const float bv = bias[bc & 63];
            const bool colInt = (bx == 1) | (bx == 2);
            float f[8];
#pragma unroll
            for (int j = 0; j < 8; ++j) {
                const int c = 8 * c6 + j;              // local col 0..47
                bool valid = c < 43;
                if (!colInt) valid = valid && ((unsigned)(j0 - 5 + c) < 128u);
                const float xv = (j < 4) ? v0[j] : v1[j - 4];
                f[j] = valid ? xv + bv : 0.f;
            }
            *(int4*)dst = make_int4(pack_bf2(f[0], f[1]), pack_bf2(f[2], f[3]),
                                    pack_bf2(f[4], f[5]), pack_bf2(f[6], f[7]));
        } else {
            *(int4*)dst = make_int4(0, 0, 0, 0);
        }
    }
    __syncthreads();

    // ---- S1: 25 tiles, one window per wave. ----
#define S1C(W) s1_phase<W>(GtB, Xl, B1t, lane, l15, q4);
    DISP8(S1C)
#undef S1C
    __syncthreads();

    // ---- S2: 45 tiles. ----
#define S2C(W) s2_phase<W>(G2A, B1t, Ut, lane, l15, q4);
    DISP8(S2C)
#undef S2C
    __syncthreads();

    // ---- S3: 20 tiles. ----
#define S3C(W) s3_phase<W>(DA, Ut, T, lane, l15, q4);
    DISP8(S3C)
#undef S3C
    __syncthreads();

    // ---- S4: 8 tiles, one per wave. ----
    const size_t obase_c = (size_t)bc * 16384;
#define S4C(W) s4_phase<W>(T, D2B, out, obase_c, i0, j0, l15, q4, lane);
    DISP8(S4C)
#undef S4C
}

extern "C" void kernel_launch(void* const* d_in, const int* in_sizes, int n_in,
                              void* d_out, int out_size, void* d_ws, size_t ws_size,
                              hipStream_t stream) {
    const float* x  = (const float*)d_in[0];
    const float* bs = (const float*)d_in[1];
    const float* fu = (const float*)d_in[2];
    const float* fd = (const float*)d_in[3];
    float* outp = (float*)d_out;
    short* ws = (short*)d_ws;

    build_consts<<<84, 256, 0, stream>>>(fu, fd, ws);    // 21504 elems
    upfirdn_mfma<<<dim3(4, 2, 512), 512, 0, stream>>>(x, bs, ws, outp);
}